// Round 11
// baseline (220.422 us; speedup 1.0000x reference)
//
#include <hip/hip_runtime.h>

typedef _Float16 f16;
typedef _Float16 f16x8 __attribute__((ext_vector_type(8)));
typedef float f32x16 __attribute__((ext_vector_type(16)));
typedef float f32x4v __attribute__((ext_vector_type(4)));
typedef unsigned long long u64;

#define NB 5
#define DIN 100
#define NT 768                     // 12 waves/block, 1 block/CU -> 3 waves/SIMD
#define GRID 256
#define NWAVES (GRID * 12)

// Homogeneous-coordinate weight fragments (bias/t folded into extra K rows):
//  W1ext[112][64]: rows<100 = dW1, row100 = db1       -> fids 0..13  (ks0..6 x mt0..1)
//  W2ext[80][64] : rows<64  = dW2, row64  = db2       -> fids 14..23 (ks0..4 x mt0..1)
//  heads, per q (base 24 + q*25):
//    L1ext[80][64]: <64 hw1, 64 hb1, 65 htw1          -> +0..9
//    L2ext[80][64]: <64 hw2, 64 hb2, 65 htw2          -> +10..19
//    L3ext[80][32]: col0: <64 hw3, 64 hb3, 65 htw3    -> +20..24 (single mt)
#define FID_W2 14
#define FID_HD 24
#define NFID   (FID_HD + NB * 25)    // 149
#define NENT   (NFID * 64)           // 9536 f16x8 entries = 152,576 B

// A-frag layout (32x32x16, r7-verified): lane l holds W[k = 16*ks + 8*(l>>5) + e][32*mt + (l&31)]
__global__ __launch_bounds__(256)
void prepack_kernel(const float* __restrict__ dW1, const float* __restrict__ db1,
                    const float* __restrict__ dW2, const float* __restrict__ db2,
                    const float* __restrict__ hw1, const float* __restrict__ htw1, const float* __restrict__ hb1,
                    const float* __restrict__ hw2, const float* __restrict__ htw2, const float* __restrict__ hb2,
                    const float* __restrict__ hw3, const float* __restrict__ htw3, const float* __restrict__ hb3,
                    f16x8* __restrict__ pw)
{
    int E = blockIdx.x * 256 + threadIdx.x;
    if (E >= NENT) return;
    const int lane = E & 63, fid = E >> 6;
    const int hi8 = (lane >> 5) * 8, m = lane & 31;
    f16x8 v;
    if (fid < FID_W2) {
        int ks = fid >> 1, mm = (fid & 1) * 32 + m;
        #pragma unroll
        for (int e = 0; e < 8; ++e) {
            int k = 16 * ks + hi8 + e;
            float val = (k < 100) ? dW1[k * 64 + mm] : (k == 100 ? db1[mm] : 0.f);
            v[e] = (f16)val;
        }
    } else if (fid < FID_HD) {
        int f = fid - FID_W2;
        int ks = f >> 1, mm = (f & 1) * 32 + m;
        #pragma unroll
        for (int e = 0; e < 8; ++e) {
            int k = 16 * ks + hi8 + e;
            float val = (k < 64) ? dW2[k * 64 + mm] : (k == 64 ? db2[mm] : 0.f);
            v[e] = (f16)val;
        }
    } else {
        int f = fid - FID_HD, q = f / 25, r = f % 25;
        if (r < 20) {
            int layer = r / 10, rr = r % 10;
            int ks = rr >> 1, mm = (rr & 1) * 32 + m;
            const float* W = layer ? hw2 : hw1;
            const float* B = layer ? hb2 : hb1;
            const float* T = layer ? htw2 : htw1;
            #pragma unroll
            for (int e = 0; e < 8; ++e) {
                int k = 16 * ks + hi8 + e;
                float val = (k < 64) ? W[q * 4096 + k * 64 + mm]
                          : (k == 64 ? B[q * 64 + mm]
                          : (k == 65 ? T[q * 64 + mm] : 0.f));
                v[e] = (f16)val;
            }
        } else {
            int ks = r - 20;
            #pragma unroll
            for (int e = 0; e < 8; ++e) {
                int k = 16 * ks + hi8 + e;
                float val = 0.f;
                if (m == 0)
                    val = (k < 64) ? hw3[q * 64 + k]
                        : (k == 64 ? hb3[q] : (k == 65 ? htw3[q] : 0.f));
                v[e] = (f16)val;
            }
        }
    }
    pw[E] = v;
}

__device__ __forceinline__ f32x16 mfma32(f16x8 a, f16x8 b, f32x16 c) {
    return __builtin_amdgcn_mfma_f32_32x32x16_f16(a, b, c, 0, 0, 0);
}
__device__ __forceinline__ f32x16 vzero() {
    f32x16 z;
    #pragma unroll
    for (int i = 0; i < 16; ++i) z[i] = 0.f;
    return z;
}
__device__ __forceinline__ unsigned pk2(float a, float b) {
    union { f16 h[2]; unsigned u; } z; z.h[0] = (f16)a; z.h[1] = (f16)b; return z.u;
}
__device__ __forceinline__ f16x8 frag4(unsigned a, unsigned b, unsigned c, unsigned d) {
    union { unsigned u[4]; f16x8 v; } z; z.u[0]=a; z.u[1]=b; z.u[2]=c; z.u[3]=d; return z.v;
}

// relu + pack only (bias/t folded into MFMA via homogeneous rows)
#define EPIR(W, A) { \
    W[0]=pk2(fmaxf(A[0],0.f), fmaxf(A[1],0.f)); \
    W[1]=pk2(fmaxf(A[2],0.f), fmaxf(A[3],0.f)); \
    W[2]=pk2(fmaxf(A[4],0.f), fmaxf(A[5],0.f)); \
    W[3]=pk2(fmaxf(A[6],0.f), fmaxf(A[7],0.f)); \
    W[4]=pk2(fmaxf(A[8],0.f), fmaxf(A[9],0.f)); \
    W[5]=pk2(fmaxf(A[10],0.f),fmaxf(A[11],0.f)); \
    W[6]=pk2(fmaxf(A[12],0.f),fmaxf(A[13],0.f)); \
    W[7]=pk2(fmaxf(A[14],0.f),fmaxf(A[15],0.f)); }

// assemble next layer's B-frag for one k-step (r7-verified; uses `lo` = lane<32)
#define MKB(dst, Wm, jb) { \
    unsigned s0_=__shfl_xor(Wm[jb+0],32,64), s1_=__shfl_xor(Wm[jb+1],32,64); \
    unsigned s2_=__shfl_xor(Wm[jb+2],32,64), s3_=__shfl_xor(Wm[jb+3],32,64); \
    dst = frag4(lo ? Wm[jb+0] : s2_, lo ? Wm[jb+1] : s3_, \
                lo ? s0_ : Wm[jb+2], lo ? s1_ : Wm[jb+3]); }

__global__ __launch_bounds__(NT, 3)
void drnet_main(const float* __restrict__ t, const float* __restrict__ x,
                const f16x8* __restrict__ pw,
                float* __restrict__ out, int N, int NG)
{
    __shared__ __align__(16) f16x8 swts[NENT];          // 152,576 B: all weight frags
    __shared__ unsigned short ssrt[12][64];
    __shared__ float sout[12][64];

    const int tid = threadIdx.x;
    const int lane = tid & 63;
    const int wv = tid >> 6;
    const int hi = lane >> 5;
    const int sm = lane & 31;
    const bool lo = (hi == 0);

    for (int p = tid; p < NENT; p += NT)
        ((float4*)swts)[p] = ((const float4*)pw)[p];
    __syncthreads();   // ONLY barrier; the main loop is fully wave-autonomous

    #define TF(fid) swts[(fid)*64 + lane]

    // trunk-L2 homogeneous frag: k=64 -> 1.0 (bias row)
    const f16x8 bfb = lo ? frag4(pk2(1.f, 0.f), 0u, 0u, 0u) : frag4(0u, 0u, 0u, 0u);

    // per-tile compute: 32 sorted samples; bias/t ride inside MFMA (r10-verified)
    auto do_tile = [&](const f16x8* xb, f16x8 bft, int li, int rq, int qlo, int qhiR) {
        if (qlo >= NB) return;
        const int qhi = min(qhiR, NB - 1);

        // trunk L1 (bias at k=100, inside existing padding): 14 MFMA
        f32x16 a0 = vzero(), a1 = vzero();
        #pragma unroll
        for (int ks = 0; ks < 7; ++ks) {
            a0 = mfma32(TF(ks*2 + 0), xb[ks], a0);
            a1 = mfma32(TF(ks*2 + 1), xb[ks], a1);
        }
        unsigned WA[8], WB[8];
        EPIR(WA, a0); EPIR(WB, a1);
        f16x8 h0, h1_, h2_, h3_;
        MKB(h0, WA, 0); MKB(h1_, WA, 4); MKB(h2_, WB, 0); MKB(h3_, WB, 4);

        // trunk L2: K=80 (bias kstep via bfb): 10 MFMA
        f32x16 c0 = vzero(), c1 = vzero();
        c0 = mfma32(TF(FID_W2+0), h0, c0);  c1 = mfma32(TF(FID_W2+1), h0, c1);
        c0 = mfma32(TF(FID_W2+2), h1_, c0); c1 = mfma32(TF(FID_W2+3), h1_, c1);
        c0 = mfma32(TF(FID_W2+4), h2_, c0); c1 = mfma32(TF(FID_W2+5), h2_, c1);
        c0 = mfma32(TF(FID_W2+6), h3_, c0); c1 = mfma32(TF(FID_W2+7), h3_, c1);
        c0 = mfma32(TF(FID_W2+8), bfb, c0); c1 = mfma32(TF(FID_W2+9), bfb, c1);
        unsigned UA[8], UB[8];
        EPIR(UA, c0); EPIR(UB, c1);
        f16x8 g0, g1, g2, g3;
        MKB(g0, UA, 0); MKB(g1, UA, 4); MKB(g2, UB, 0); MKB(g3, UB, 4);

        #pragma unroll 1
        for (int q = qlo; q <= qhi; ++q) {
            const int hf = FID_HD + q * 25;
            // head L1: K=80 ([1,t] kstep via bft): 10 MFMA
            f32x16 d0 = vzero(), d1 = vzero();
            d0 = mfma32(TF(hf+0), g0, d0);  d1 = mfma32(TF(hf+1), g0, d1);
            d0 = mfma32(TF(hf+2), g1, d0);  d1 = mfma32(TF(hf+3), g1, d1);
            d0 = mfma32(TF(hf+4), g2, d0);  d1 = mfma32(TF(hf+5), g2, d1);
            d0 = mfma32(TF(hf+6), g3, d0);  d1 = mfma32(TF(hf+7), g3, d1);
            d0 = mfma32(TF(hf+8), bft, d0); d1 = mfma32(TF(hf+9), bft, d1);
            unsigned VA[8], VB[8];
            EPIR(VA, d0); EPIR(VB, d1);
            f16x8 e0, e1, e2, e3;
            MKB(e0, VA, 0); MKB(e1, VA, 4); MKB(e2, VB, 0); MKB(e3, VB, 4);

            // head L2: 10 MFMA
            f32x16 f0 = vzero(), f1 = vzero();
            f0 = mfma32(TF(hf+10), e0, f0);  f1 = mfma32(TF(hf+11), e0, f1);
            f0 = mfma32(TF(hf+12), e1, f0);  f1 = mfma32(TF(hf+13), e1, f1);
            f0 = mfma32(TF(hf+14), e2, f0);  f1 = mfma32(TF(hf+15), e2, f1);
            f0 = mfma32(TF(hf+16), e3, f0);  f1 = mfma32(TF(hf+17), e3, f1);
            f0 = mfma32(TF(hf+18), bft, f0); f1 = mfma32(TF(hf+19), bft, f1);
            unsigned YA[8], YB[8];
            EPIR(YA, f0); EPIR(YB, f1);
            f16x8 z0, z1, z2, z3;
            MKB(z0, YA, 0); MKB(z1, YA, 4); MKB(z2, YB, 0); MKB(z3, YB, 4);

            // head L3 as MFMA column (w3 dot + hb3 + t*htw3): 5 MFMA; out = row0
            f32x16 o0 = vzero();
            o0 = mfma32(TF(hf+20), z0, o0);
            o0 = mfma32(TF(hf+21), z1, o0);
            o0 = mfma32(TF(hf+22), z2, o0);
            o0 = mfma32(TF(hf+23), z3, o0);
            o0 = mfma32(TF(hf+24), bft, o0);
            if (lo && rq == q)
                sout[wv][li] = o0[0];      // row0 = reg0, hi=0; col = lane = sample
        }
    };

    // wave-local ballot counting sort of one 64-sample window (r7-verified; no sstv)
    auto sortw = [&](int gn, float tvn) {
        const int i0 = gn * 64 + lane;
        const int qme = (i0 < N) ? min((int)(tvn * 5.0f), NB - 1) : NB;
        const u64 lowm = (1ull << lane) - 1ull;
        int pos = 0;
        #pragma unroll
        for (int b = 0; b <= NB; ++b) {
            u64 mb = __ballot(qme == b);
            int ca = __popcll(mb), cb = __popcll(mb & lowm);
            pos += (b < qme) ? ca : ((b == qme) ? cb : 0);
        }
        ssrt[wv][pos] = (unsigned short)(lane | (qme << 8));
        __asm__ volatile("s_waitcnt lgkmcnt(0)" ::: "memory");
    };

    // non-temporal x gather (streaming, no reuse -> don't allocate cache)
    auto issue_x = [&](f32x4v* r, int gn, int li) {
        const f32x4v* xp = (const f32x4v*)(x + (size_t)min(gn * 64 + li, N - 1) * DIN);
        #pragma unroll
        for (int ks = 0; ks < 6; ++ks) {
            r[2*ks]   = __builtin_nontemporal_load(xp + 4*ks + 2*hi);
            r[2*ks+1] = __builtin_nontemporal_load(xp + 4*ks + 2*hi + 1);
        }
        if (lo) r[12] = __builtin_nontemporal_load(xp + 24);
        else    { f32x4v z = {0.f,0.f,0.f,0.f}; r[12] = z; }
    };

    auto convert = [&](f16x8* xb, const f32x4v* r) {
        #pragma unroll
        for (int ks = 0; ks < 6; ++ks)
            xb[ks] = frag4(pk2(r[2*ks][0], r[2*ks][1]),   pk2(r[2*ks][2], r[2*ks][3]),
                           pk2(r[2*ks+1][0], r[2*ks+1][1]), pk2(r[2*ks+1][2], r[2*ks+1][3]));
        // k=100 is the homogeneous 1.0 (bias row of W1ext); k>100 zero
        xb[6] = frag4(pk2(r[12][0], r[12][1]), pk2(r[12][2], r[12][3]),
                      lo ? pk2(1.0f, 0.f) : 0u, 0u);
    };

    const int gw = blockIdx.x * 12 + wv;
    const int S = NWAVES;

    f32x4v raw[13];
    float tcur = 0.f, treg = 0.f;
    int g = gw;
    if (g < NG) {
        tcur = __builtin_nontemporal_load(&t[min(g * 64 + lane, N - 1)]);
        sortw(g, tcur);                                   // window g sorted
        { int li = ssrt[wv][sm] & 63; issue_x(raw, g, li); }   // T0(g) in flight
        { int gn = g + S; treg = (gn < NG) ? __builtin_nontemporal_load(&t[min(gn * 64 + lane, N - 1)]) : 0.f; }
    }

    // INVARIANT at loop top: ssrt = window g; raw = T0(g) in flight; tcur = t(g); treg = t(g+S)
    #pragma unroll 1
    for (; g < NG; g += S) {
        const unsigned short pk0 = ssrt[wv][sm], pk1 = ssrt[wv][32 + sm];
        const int li0 = pk0 & 63, rq0 = pk0 >> 8;
        const int li1 = pk1 & 63, rq1 = pk1 >> 8;
        const float rt0 = __shfl(tcur, li0, 64);
        const float rt1 = __shfl(tcur, li1, 64);
        const int qlo0 = ssrt[wv][0]  >> 8, qh0 = ssrt[wv][31] >> 8;
        const int qlo1 = ssrt[wv][32] >> 8, qh1 = ssrt[wv][63] >> 8;
        const f16x8 bft0 = lo ? frag4(pk2(1.f, rt0), 0u, 0u, 0u) : frag4(0u, 0u, 0u, 0u);
        const f16x8 bft1 = lo ? frag4(pk2(1.f, rt1), 0u, 0u, 0u) : frag4(0u, 0u, 0u, 0u);

        f16x8 xb[7];
        convert(xb, raw);                      // waits T0(g) loads; raw regs freed
        issue_x(raw, g, li1);                  // T1(g) in flight; covered by tile-0 compute
        __builtin_amdgcn_sched_barrier(0);     // pin: loads issued before tile0 compute
        do_tile(xb, bft0, li0, rq0, qlo0, qh0);
        __builtin_amdgcn_sched_barrier(0);

        const bool last = (g + S >= NG);
        if (!last) {
            sortw(g + S, treg);                // next window's sort (t prefetched 1 window ago)
            tcur = treg;
            { int gn2 = g + 2 * S; treg = (gn2 < NG) ? __builtin_nontemporal_load(&t[min(gn2 * 64 + lane, N - 1)]) : 0.f; }
        }
        convert(xb, raw);                      // waits T1(g); covered by tile-0 compute
        if (!last) {
            int li = ssrt[wv][sm] & 63;
            issue_x(raw, g + S, li);           // T0(g+S) in flight; covered by tile-1 compute
        }
        __builtin_amdgcn_sched_barrier(0);     // pin: loads issued before tile1 compute
        do_tile(xb, bft1, li1, rq1, qlo1, qh1);

        __asm__ volatile("s_waitcnt lgkmcnt(0)" ::: "memory");
        const int ig = g * 64 + lane;
        if (ig < N) out[ig] = sout[wv][lane];  // coalesced flush
    }
    #undef TF
}

extern "C" void kernel_launch(void* const* d_in, const int* in_sizes, int n_in,
                              void* d_out, int out_size, void* d_ws, size_t ws_size,
                              hipStream_t stream) {
    const float* t    = (const float*)d_in[0];
    const float* x    = (const float*)d_in[1];
    const float* dW1  = (const float*)d_in[2];
    const float* db1  = (const float*)d_in[3];
    const float* dW2  = (const float*)d_in[4];
    const float* db2  = (const float*)d_in[5];
    const float* hw1  = (const float*)d_in[6];
    const float* htw1 = (const float*)d_in[7];
    const float* hb1  = (const float*)d_in[8];
    const float* hw2  = (const float*)d_in[9];
    const float* htw2 = (const float*)d_in[10];
    const float* hb2  = (const float*)d_in[11];
    const float* hw3  = (const float*)d_in[12];
    const float* htw3 = (const float*)d_in[13];
    const float* hb3  = (const float*)d_in[14];
    float* out = (float*)d_out;

    const int N = in_sizes[0];
    const int NG = (N + 63) / 64;
    f16x8* pw = (f16x8*)d_ws;   // NENT * 16 B = 152,576 B

    prepack_kernel<<<(NENT + 255) / 256, 256, 0, stream>>>(
        dW1, db1, dW2, db2, hw1, htw1, hb1, hw2, htw2, hb2, hw3, htw3, hb3, pw);
    drnet_main<<<GRID, NT, 0, stream>>>(t, x, pw, out, N, NG);
}

// Round 12
// 164.349 us; speedup vs baseline: 1.3412x; 1.3412x over previous
//
#include <hip/hip_runtime.h>

typedef _Float16 f16;
typedef _Float16 f16x8 __attribute__((ext_vector_type(8)));
typedef float f32x16 __attribute__((ext_vector_type(16)));
typedef float f32x4v __attribute__((ext_vector_type(4)));
typedef unsigned long long u64;

#define NB 5
#define DIN 100
#define SEG 4096
#define AB 153                       // blocks per army
#define GRID_MAIN (NB * AB)          // 765
#define TSTRIDE 8192                 // tmap stride per army (>= max tiles/army ~6500)

// Homogeneous-coordinate weight fragments (bias/t folded into extra K rows), r10-verified:
//  W1ext[112][64]: rows<100 = dW1, row100 = db1       -> fids 0..13
//  W2ext[80][64] : rows<64  = dW2, row64  = db2       -> fids 14..23
//  heads, per q (base 24 + q*25): L1ext 0..9, L2ext 10..19, L3ext col0 20..24
#define FID_W2 14
#define FID_HD 24
#define NFID   (FID_HD + NB * 25)    // 149
#define NENT   (NFID * 64)           // 9536 f16x8 = 152,576 B

__global__ __launch_bounds__(256)
void prepack_kernel(const float* __restrict__ dW1, const float* __restrict__ db1,
                    const float* __restrict__ dW2, const float* __restrict__ db2,
                    const float* __restrict__ hw1, const float* __restrict__ htw1, const float* __restrict__ hb1,
                    const float* __restrict__ hw2, const float* __restrict__ htw2, const float* __restrict__ hb2,
                    const float* __restrict__ hw3, const float* __restrict__ htw3, const float* __restrict__ hb3,
                    f16x8* __restrict__ pw)
{
    int E = blockIdx.x * 256 + threadIdx.x;
    if (E >= NENT) return;
    const int lane = E & 63, fid = E >> 6;
    const int hi8 = (lane >> 5) * 8, m = lane & 31;
    f16x8 v;
    if (fid < FID_W2) {
        int ks = fid >> 1, mm = (fid & 1) * 32 + m;
        #pragma unroll
        for (int e = 0; e < 8; ++e) {
            int k = 16 * ks + hi8 + e;
            float val = (k < 100) ? dW1[k * 64 + mm] : (k == 100 ? db1[mm] : 0.f);
            v[e] = (f16)val;
        }
    } else if (fid < FID_HD) {
        int f = fid - FID_W2;
        int ks = f >> 1, mm = (f & 1) * 32 + m;
        #pragma unroll
        for (int e = 0; e < 8; ++e) {
            int k = 16 * ks + hi8 + e;
            float val = (k < 64) ? dW2[k * 64 + mm] : (k == 64 ? db2[mm] : 0.f);
            v[e] = (f16)val;
        }
    } else {
        int f = fid - FID_HD, q = f / 25, r = f % 25;
        if (r < 20) {
            int layer = r / 10, rr = r % 10;
            int ks = rr >> 1, mm = (rr & 1) * 32 + m;
            const float* W = layer ? hw2 : hw1;
            const float* B = layer ? hb2 : hb1;
            const float* T = layer ? htw2 : htw1;
            #pragma unroll
            for (int e = 0; e < 8; ++e) {
                int k = 16 * ks + hi8 + e;
                float val = (k < 64) ? W[q * 4096 + k * 64 + mm]
                          : (k == 64 ? B[q * 64 + mm]
                          : (k == 65 ? T[q * 64 + mm] : 0.f));
                v[e] = (f16)val;
            }
        } else {
            int ks = r - 20;
            #pragma unroll
            for (int e = 0; e < 8; ++e) {
                int k = 16 * ks + hi8 + e;
                float val = 0.f;
                if (m == 0)
                    val = (k < 64) ? hw3[q * 64 + k]
                        : (k == 64 ? hb3[q] : (k == 65 ? htw3[q] : 0.f));
                v[e] = (f16)val;
            }
        }
    }
    pw[E] = v;
}

// ---------------- segment-local counting sort ----------------
__global__ __launch_bounds__(256)
void hist_kernel(const float* __restrict__ t, int* __restrict__ bh, int N)
{
    __shared__ int h[NB];
    if (threadIdx.x < NB) h[threadIdx.x] = 0;
    __syncthreads();
    const int s0 = blockIdx.x * SEG;
    const int e = min(SEG, N - s0);
    for (int p = threadIdx.x; p < e; p += 256) {
        int b = min((int)(t[s0 + p] * 5.0f), NB - 1);
        atomicAdd(&h[b], 1);
    }
    __syncthreads();
    if (threadIdx.x < NB) bh[blockIdx.x * NB + threadIdx.x] = h[threadIdx.x];
}

__global__ __launch_bounds__(256)
void scan_kernel(const int* __restrict__ bh, int* __restrict__ offl,
                 int* __restrict__ ends, int* __restrict__ ntl,
                 int* __restrict__ tstart, int* __restrict__ atile,
                 int* __restrict__ tmap, int nsb)
{
    const int tid = threadIdx.x;
    // step1: per-segment local prefix over bins
    for (int s = tid; s < nsb; s += 256) {
        int run = 0;
        #pragma unroll
        for (int b = 0; b < NB; ++b) {
            int c = bh[s * NB + b];
            offl[s * NB + b] = run;
            run += c;
            ends[s * NB + b] = run;
            ntl[s * NB + b] = (c + 31) >> 5;
        }
    }
    __syncthreads();
    // step2: per-bin prefix of tile counts over segments
    if (tid < NB) {
        int run = 0;
        for (int s = 0; s < nsb; ++s) { tstart[s * NB + tid] = run; run += ntl[s * NB + tid]; }
        atile[tid] = run;
    }
    __syncthreads();
    // step3: fill tile map: entry = global slot of tile start (seg*SEG + local offset)
    const int total = nsb * NB;
    for (int i = tid; i < total; i += 256) {
        int s = i / NB, q = i % NB;
        int o = offl[i], nt = ntl[i], ts = tstart[i];
        for (int k = 0; k < nt; ++k)
            tmap[q * TSTRIDE + ts + k] = s * SEG + o + 32 * k;
    }
}

__global__ __launch_bounds__(256)
void scatter_kernel(const float* __restrict__ t, const int* __restrict__ offl,
                    int* __restrict__ perm, int N)
{
    __shared__ int lcur[NB];
    if (threadIdx.x < NB) lcur[threadIdx.x] = offl[blockIdx.x * NB + threadIdx.x];
    __syncthreads();
    const int s0 = blockIdx.x * SEG;
    const int e = min(SEG, N - s0);
    for (int p = threadIdx.x; p < e; p += 256) {
        float tv = t[s0 + p];
        int b = min((int)(tv * 5.0f), NB - 1);
        int slot = atomicAdd(&lcur[b], 1);
        perm[(size_t)blockIdx.x * SEG + slot] = s0 + p;
    }
}

// ---------------- main ----------------
__device__ __forceinline__ f32x16 mfma32(f16x8 a, f16x8 b, f32x16 c) {
    return __builtin_amdgcn_mfma_f32_32x32x16_f16(a, b, c, 0, 0, 0);
}
__device__ __forceinline__ f32x16 vzero() {
    f32x16 z;
    #pragma unroll
    for (int i = 0; i < 16; ++i) z[i] = 0.f;
    return z;
}
__device__ __forceinline__ unsigned pk2(float a, float b) {
    union { f16 h[2]; unsigned u; } z; z.h[0] = (f16)a; z.h[1] = (f16)b; return z.u;
}
__device__ __forceinline__ f16x8 frag4(unsigned a, unsigned b, unsigned c, unsigned d) {
    union { unsigned u[4]; f16x8 v; } z; z.u[0]=a; z.u[1]=b; z.u[2]=c; z.u[3]=d; return z.v;
}

#define EPIR(W, A) { \
    W[0]=pk2(fmaxf(A[0],0.f), fmaxf(A[1],0.f)); \
    W[1]=pk2(fmaxf(A[2],0.f), fmaxf(A[3],0.f)); \
    W[2]=pk2(fmaxf(A[4],0.f), fmaxf(A[5],0.f)); \
    W[3]=pk2(fmaxf(A[6],0.f), fmaxf(A[7],0.f)); \
    W[4]=pk2(fmaxf(A[8],0.f), fmaxf(A[9],0.f)); \
    W[5]=pk2(fmaxf(A[10],0.f),fmaxf(A[11],0.f)); \
    W[6]=pk2(fmaxf(A[12],0.f),fmaxf(A[13],0.f)); \
    W[7]=pk2(fmaxf(A[14],0.f),fmaxf(A[15],0.f)); }

#define MKB(dst, Wm, jb) { \
    unsigned s0_=__shfl_xor(Wm[jb+0],32,64), s1_=__shfl_xor(Wm[jb+1],32,64); \
    unsigned s2_=__shfl_xor(Wm[jb+2],32,64), s3_=__shfl_xor(Wm[jb+3],32,64); \
    dst = frag4(lo ? Wm[jb+0] : s2_, lo ? Wm[jb+1] : s3_, \
                lo ? s0_ : Wm[jb+2], lo ? s1_ : Wm[jb+3]); }

// LDS weight map: 0..13 W1ext, 14..23 W2ext, 24..33 hL1, 34..43 hL2, 44..48 hL3
#define NSW 49

__global__ __launch_bounds__(256, 3)
void drnet_main(const float* __restrict__ t, const float* __restrict__ x,
                const f16x8* __restrict__ pw,
                const int* __restrict__ tmap, const int* __restrict__ ends,
                const int* __restrict__ atile, const int* __restrict__ perm,
                float* __restrict__ out, int N)
{
    __shared__ __align__(16) f16x8 sw[NSW * 64];    // 50,176 B

    const int tid = threadIdx.x;
    const int lane = tid & 63;
    const int wv = tid >> 6;
    const int hi = lane >> 5;
    const int sm = lane & 31;
    const bool lo = (hi == 0);

    const int q = blockIdx.x / AB;

    // stage trunk + my head's frags into LDS
    for (int p = tid; p < 24 * 64; p += 256)
        ((float4*)sw)[p] = ((const float4*)pw)[p];
    for (int p = tid; p < 25 * 64; p += 256)
        ((float4*)(sw + 24 * 64))[p] = ((const float4*)(pw + (FID_HD + q * 25) * 64))[p];
    __syncthreads();      // ONLY barrier; main loop is wave-autonomous

    #define TF(fid) sw[(fid)*64 + lane]

    const f16x8 zf = frag4(0u, 0u, 0u, 0u);
    const f16x8 bfb = lo ? frag4(pk2(1.f, 0.f), 0u, 0u, 0u) : zf;

    const int njq = atile[q];
    const int* tm = tmap + q * TSTRIDE;
    const int JS = AB * 4;                       // 612 waves per army
    int j = (blockIdx.x % AB) * 4 + wv;          // this wave's first tile (< 612 <= njq)

    auto cntof = [&](int e) -> int {
        int s = e >> 12;
        return min(32, ends[s * NB + q] - (e & (SEG - 1)));
    };
    auto issue_x = [&](f32x4v* r, int pidx) {
        const f32x4v* xp = (const f32x4v*)(x + (size_t)pidx * DIN);
        #pragma unroll
        for (int ks = 0; ks < 6; ++ks) { r[2*ks] = xp[4*ks + 2*hi]; r[2*ks+1] = xp[4*ks + 2*hi + 1]; }
        if (lo) r[12] = xp[24];
        else    { f32x4v z = {0.f,0.f,0.f,0.f}; r[12] = z; }
    };
    auto convert = [&](f16x8* xb, const f32x4v* r) {
        #pragma unroll
        for (int ks = 0; ks < 6; ++ks)
            xb[ks] = frag4(pk2(r[2*ks][0], r[2*ks][1]),   pk2(r[2*ks][2], r[2*ks][3]),
                           pk2(r[2*ks+1][0], r[2*ks+1][1]), pk2(r[2*ks+1][2], r[2*ks+1][3]));
        xb[6] = frag4(pk2(r[12][0], r[12][1]), pk2(r[12][2], r[12][3]),
                      lo ? pk2(1.0f, 0.f) : 0u, 0u);
    };
    #define TMAP(jj) tm[min(jj, njq - 1)]

    // ---- prologue: tiles j (full chain) and j+1 (perm in flight), tmap(j+2) ----
    f32x4v raw[13];
    int eA = TMAP(j);
    int eB = TMAP(j + JS);
    int eC_pend = TMAP(j + 2 * JS);
    int cntA = cntof(eA);
    int pA = perm[eA + min(sm, cntA - 1)];
    float tA = t[pA];
    issue_x(raw, pA);
    int cntB = cntof(eB);
    int pB_pend = perm[eB + min(sm, cntB - 1)];

    #pragma unroll 1
    for (; j < njq; j += JS) {
        // phase 1: convert x(j) (waits its loads; 1 phase old in steady state)
        f16x8 xb[7];
        convert(xb, raw);
        const f16x8 bft = lo ? frag4(pk2(1.f, tA), 0u, 0u, 0u) : zf;
        const int storeP = pA, storeCnt = cntA;
        __builtin_amdgcn_sched_barrier(0);

        // phase 2: advance the 3-stage fetch pipeline (each link 1 phase old)
        const int pB = pB_pend;                  // perm(j+1) value (issued last iter)
        const float tB = t[pB];                  // t(j+1) in flight, used next iter
        issue_x(raw, pB);                        // x(j+1) in flight through compute
        const int eC = eC_pend;                  // tmap(j+2) value
        const int cntC = cntof(eC);
        const int pC_pend = perm[eC + min(sm, cntC - 1)];   // perm(j+2) in flight
        const int eD = TMAP(j + 3 * JS);         // tmap(j+3) in flight
        __builtin_amdgcn_sched_barrier(0);

        // phase 3: compute tile j (fixed head q; bias/t inside MFMA)
        {
            // trunk L1: 14 MFMA
            f32x16 a0 = vzero(), a1 = vzero();
            #pragma unroll
            for (int ks = 0; ks < 7; ++ks) {
                a0 = mfma32(TF(ks*2 + 0), xb[ks], a0);
                a1 = mfma32(TF(ks*2 + 1), xb[ks], a1);
            }
            unsigned WA[8], WB[8];
            EPIR(WA, a0); EPIR(WB, a1);
            f16x8 h0, h1_, h2_, h3_;
            MKB(h0, WA, 0); MKB(h1_, WA, 4); MKB(h2_, WB, 0); MKB(h3_, WB, 4);

            // trunk L2: 10 MFMA
            f32x16 c0 = vzero(), c1 = vzero();
            c0 = mfma32(TF(14), h0, c0);  c1 = mfma32(TF(15), h0, c1);
            c0 = mfma32(TF(16), h1_, c0); c1 = mfma32(TF(17), h1_, c1);
            c0 = mfma32(TF(18), h2_, c0); c1 = mfma32(TF(19), h2_, c1);
            c0 = mfma32(TF(20), h3_, c0); c1 = mfma32(TF(21), h3_, c1);
            c0 = mfma32(TF(22), bfb, c0); c1 = mfma32(TF(23), bfb, c1);
            unsigned UA[8], UB[8];
            EPIR(UA, c0); EPIR(UB, c1);
            f16x8 g0, g1, g2, g3;
            MKB(g0, UA, 0); MKB(g1, UA, 4); MKB(g2, UB, 0); MKB(g3, UB, 4);

            // head L1: 10 MFMA
            f32x16 d0 = vzero(), d1 = vzero();
            d0 = mfma32(TF(24), g0, d0);  d1 = mfma32(TF(25), g0, d1);
            d0 = mfma32(TF(26), g1, d0);  d1 = mfma32(TF(27), g1, d1);
            d0 = mfma32(TF(28), g2, d0);  d1 = mfma32(TF(29), g2, d1);
            d0 = mfma32(TF(30), g3, d0);  d1 = mfma32(TF(31), g3, d1);
            d0 = mfma32(TF(32), bft, d0); d1 = mfma32(TF(33), bft, d1);
            unsigned VA[8], VB[8];
            EPIR(VA, d0); EPIR(VB, d1);
            f16x8 e0, e1, e2, e3;
            MKB(e0, VA, 0); MKB(e1, VA, 4); MKB(e2, VB, 0); MKB(e3, VB, 4);

            // head L2: 10 MFMA
            f32x16 f0 = vzero(), f1 = vzero();
            f0 = mfma32(TF(34), e0, f0);  f1 = mfma32(TF(35), e0, f1);
            f0 = mfma32(TF(36), e1, f0);  f1 = mfma32(TF(37), e1, f1);
            f0 = mfma32(TF(38), e2, f0);  f1 = mfma32(TF(39), e2, f1);
            f0 = mfma32(TF(40), e3, f0);  f1 = mfma32(TF(41), e3, f1);
            f0 = mfma32(TF(42), bft, f0); f1 = mfma32(TF(43), bft, f1);
            unsigned YA[8], YB[8];
            EPIR(YA, f0); EPIR(YB, f1);
            f16x8 z0, z1, z2, z3;
            MKB(z0, YA, 0); MKB(z1, YA, 4); MKB(z2, YB, 0); MKB(z3, YB, 4);

            // head L3 as MFMA column: 5 MFMA; out = C[row0][col sm]
            f32x16 o0 = vzero();
            o0 = mfma32(TF(44), z0, o0);
            o0 = mfma32(TF(45), z1, o0);
            o0 = mfma32(TF(46), z2, o0);
            o0 = mfma32(TF(47), z3, o0);
            o0 = mfma32(TF(48), bft, o0);
            if (lo && sm < storeCnt)
                out[storeP] = o0[0];
        }
        __builtin_amdgcn_sched_barrier(0);

        // rotate pipeline state
        pA = pB; tA = tB; cntA = cntB;
        cntB = cntC;
        pB_pend = pC_pend;
        eC_pend = eD;
    }
    #undef TF
    #undef TMAP
}

extern "C" void kernel_launch(void* const* d_in, const int* in_sizes, int n_in,
                              void* d_out, int out_size, void* d_ws, size_t ws_size,
                              hipStream_t stream) {
    const float* t    = (const float*)d_in[0];
    const float* x    = (const float*)d_in[1];
    const float* dW1  = (const float*)d_in[2];
    const float* db1  = (const float*)d_in[3];
    const float* dW2  = (const float*)d_in[4];
    const float* db2  = (const float*)d_in[5];
    const float* hw1  = (const float*)d_in[6];
    const float* htw1 = (const float*)d_in[7];
    const float* hb1  = (const float*)d_in[8];
    const float* hw2  = (const float*)d_in[9];
    const float* htw2 = (const float*)d_in[10];
    const float* hb2  = (const float*)d_in[11];
    const float* hw3  = (const float*)d_in[12];
    const float* htw3 = (const float*)d_in[13];
    const float* hb3  = (const float*)d_in[14];
    float* out = (float*)d_out;

    const int N = in_sizes[0];
    const int nsb = (N + SEG - 1) / SEG;

    // d_ws layout
    char* ws = (char*)d_ws;
    size_t off = 0;
    f16x8* pw = (f16x8*)(ws + off);  off += (size_t)NENT * 16;            // 152,576
    auto alloc_i = [&](size_t n) { int* p = (int*)(ws + off); off += (n * 4 + 15) & ~(size_t)15; return p; };
    int* bh     = alloc_i((size_t)nsb * NB);
    int* offl   = alloc_i((size_t)nsb * NB);
    int* ends   = alloc_i((size_t)nsb * NB);
    int* ntl    = alloc_i((size_t)nsb * NB);
    int* tstart = alloc_i((size_t)nsb * NB);
    int* atile  = alloc_i(8);
    int* tmap   = alloc_i((size_t)NB * TSTRIDE);
    int* perm   = alloc_i((size_t)nsb * SEG);

    prepack_kernel<<<(NENT + 255) / 256, 256, 0, stream>>>(
        dW1, db1, dW2, db2, hw1, htw1, hb1, hw2, htw2, hb2, hw3, htw3, hb3, pw);
    hist_kernel<<<nsb, 256, 0, stream>>>(t, bh, N);
    scan_kernel<<<1, 256, 0, stream>>>(bh, offl, ends, ntl, tstart, atile, tmap, nsb);
    scatter_kernel<<<nsb, 256, 0, stream>>>(t, offl, perm, N);
    drnet_main<<<GRID_MAIN, 256, 0, stream>>>(t, x, pw, tmap, ends, atile, perm, out, N);
}